// Round 1
// baseline (476.459 us; speedup 1.0000x reference)
//
#include <hip/hip_runtime.h>
#include <hip/hip_bf16.h>

// GCN layer on MI355X.
//   pass 1 (gcn_prep): rowsum(adj)+1 -> dinv; yT[f][j] = bf16(dinv_j * x[j][f]);
//                      Wb = bf16(W)
//   pass 2 (gcn_main): h0 = adj @ y  (bf16 MFMA, adj converted on the fly)
//                      t  = dinv_i*h0 + dinv_i^2*x   (self-loop term)
//                      z  = t @ W^T + b ; out = z / max(||z||_2, eps)
//
// ws layout: [0,2MB) yT (128x8192 bf16) | [2MB,+32KB) dinv f32 | +32KB Wb bf16

typedef __attribute__((ext_vector_type(8))) short short8;     // 8 x bf16 (4 VGPR)
typedef __attribute__((ext_vector_type(4))) float f32x4;      // MFMA acc
typedef __attribute__((ext_vector_type(4))) unsigned short us4;

static __device__ __forceinline__ unsigned short f2bf(float f) {
    // round-to-nearest-even bf16
    unsigned int u = __float_as_uint(f);
    u += 0x7FFFu + ((u >> 16) & 1u);
    return (unsigned short)(u >> 16);
}

// ---------------------------------------------------------------- pass 1 ----
__global__ __launch_bounds__(256) void gcn_prep(
    const float* __restrict__ adj, const float* __restrict__ x,
    const float* __restrict__ W,
    unsigned short* __restrict__ yT, float* __restrict__ dinv,
    unsigned short* __restrict__ Wb)
{
    const int tid = threadIdx.x;
    const int blk = blockIdx.x;
    if (blk >= 8192) {                      // tail blocks: convert W -> bf16
        int idx = (blk - 8192) * 256 + tid; // 64 blocks * 256 = 16384 = 128*128
        Wb[idx] = f2bf(W[idx]);
        return;
    }
    const long j = blk;
    const float4* row = (const float4*)(adj + j * 8192L);
    float s = 0.f;
#pragma unroll
    for (int it = 0; it < 8; ++it) {        // 256 thr * 8 it * 4 = 8192 floats
        float4 v = row[it * 256 + tid];
        s += v.x + v.y + v.z + v.w;
    }
    for (int off = 1; off < 64; off <<= 1) s += __shfl_xor(s, off, 64);
    __shared__ float ps[4];
    __shared__ float sdi;
    if ((tid & 63) == 0) ps[tid >> 6] = s;
    __syncthreads();
    if (tid == 0) {
        float tot = ps[0] + ps[1] + ps[2] + ps[3] + 1.0f;  // +1: self loop
        float di = rsqrtf(tot);
        dinv[j] = di;
        sdi = di;
    }
    __syncthreads();
    if (tid < 128) {
        // scattered 2B stores (stride 16KB) — tiny total (2MB), L2 combines
        yT[(long)tid * 8192 + j] = f2bf(sdi * x[j * 128 + tid]);
    }
}

// ---------------------------------------------------------------- pass 2 ----
#define M_TILE 32
#define BKC    512           // K per chunk
#define NCHUNK 16            // 8192 / 512

__global__ __launch_bounds__(256, 1) void gcn_main(
    const float* __restrict__ adj, const float* __restrict__ x,
    const float* __restrict__ bias,
    const unsigned short* __restrict__ yT, const float* __restrict__ dinv,
    const unsigned short* __restrict__ Wb, float* __restrict__ out)
{
    __shared__ unsigned short Ab[2][M_TILE][BKC];   // 2 x 32KB = 64KB (cap)

    const int tid  = threadIdx.x;
    const int wave = tid >> 6;
    const int lane = tid & 63;
    const int q    = lane >> 4;       // quad 0..3
    const int ln   = lane & 15;
    const int nb   = wave * 32;       // this wave's N slice
    const long rowBase = (long)blockIdx.x * M_TILE;

    f32x4 acc[2][2] = {};             // [mi][nj] : (32 rows) x (32 cols)
    float4 st[16];                    // staged fp32 adj (16KB/wave per chunk)

    // stage-load: issue 16 x dwordx4 for chunk c (fire and forget)
    auto load_chunk = [&](int c) {
#pragma unroll
        for (int i = 0; i < 16; ++i) {
            int t   = wave * 16 + i;          // 0..63 insts over block
            int row = t >> 1;                 // 2 insts per 512-float row
            int col = ((t & 1) << 8) + (lane << 2);
            st[i] = *(const float4*)&adj[(rowBase + row) * 8192L + (long)c * BKC + col];
        }
    };
    // convert + write staged chunk into LDS buffer
    auto write_chunk = [&](int buf) {
#pragma unroll
        for (int i = 0; i < 16; ++i) {
            int t   = wave * 16 + i;
            int row = t >> 1;
            int col = ((t & 1) << 8) + (lane << 2);
            us4 w4;
            w4.x = f2bf(st[i].x); w4.y = f2bf(st[i].y);
            w4.z = f2bf(st[i].z); w4.w = f2bf(st[i].w);
            *(us4*)&Ab[buf][row][col] = w4;
        }
    };

    load_chunk(0);
    write_chunk(0);
    __syncthreads();

#pragma unroll 1
    for (int c = 0; c < NCHUNK; ++c) {
        const int cur = c & 1;
        if (c + 1 < NCHUNK) load_chunk(c + 1);      // in flight during compute
#pragma unroll 4
        for (int s = 0; s < BKC / 32; ++s) {        // 16 K-steps of 32
            const int k0 = s * 32 + q * 8;
            short8 a0 = *(const short8*)&Ab[cur][ln][k0];
            short8 a1 = *(const short8*)&Ab[cur][16 + ln][k0];
            const long kg = (long)c * BKC + k0;
            short8 b0 = *(const short8*)&yT[(nb + ln) * 8192L + kg];
            short8 b1 = *(const short8*)&yT[(nb + 16 + ln) * 8192L + kg];
            acc[0][0] = __builtin_amdgcn_mfma_f32_16x16x32_bf16(a0, b0, acc[0][0], 0, 0, 0);
            acc[0][1] = __builtin_amdgcn_mfma_f32_16x16x32_bf16(a0, b1, acc[0][1], 0, 0, 0);
            acc[1][0] = __builtin_amdgcn_mfma_f32_16x16x32_bf16(a1, b0, acc[1][0], 0, 0, 0);
            acc[1][1] = __builtin_amdgcn_mfma_f32_16x16x32_bf16(a1, b1, acc[1][1], 0, 0, 0);
        }
        if (c + 1 < NCHUNK) write_chunk(cur ^ 1);   // waitcnt lands here, after compute
        __syncthreads();
    }

    // ---- fused epilogue (scratch overlays Ab[0]; last compute read Ab[1]) ----
    unsigned short* t_lds = &Ab[0][0][0];           // [32][136] bf16 (pad 8)
    float* s_dinv = (float*)(t_lds + 32 * 136);
    float* s_part = s_dinv + 32;                    // [32][4] per-wave |z|^2
    float* s_inv  = s_part + 128;                   // [32]

    if (tid < 32) s_dinv[tid] = dinv[rowBase + tid];
    __syncthreads();

    // t = dinv_i * (adj@y)_i + dinv_i^2 * x_i  -> LDS (bf16)
#pragma unroll
    for (int mi = 0; mi < 2; ++mi)
#pragma unroll
        for (int nj = 0; nj < 2; ++nj)
#pragma unroll
            for (int r = 0; r < 4; ++r) {
                int m = mi * 16 + q * 4 + r;
                int n = nb + nj * 16 + ln;
                float di = s_dinv[m];
                float tv = di * acc[mi][nj][r] + di * di * x[(rowBase + m) * 128 + n];
                t_lds[m * 136 + n] = f2bf(tv);
            }
    __syncthreads();

    // z = t @ W^T via MFMA (B = Wb rows are contiguous in k)
    f32x4 z[2][2] = {};
#pragma unroll
    for (int s = 0; s < 4; ++s) {
        const int k0 = s * 32 + q * 8;
        short8 a0 = *(const short8*)&t_lds[ln * 136 + k0];
        short8 a1 = *(const short8*)&t_lds[(16 + ln) * 136 + k0];
        short8 b0 = *(const short8*)&Wb[(nb + ln) * 128 + k0];
        short8 b1 = *(const short8*)&Wb[(nb + 16 + ln) * 128 + k0];
        z[0][0] = __builtin_amdgcn_mfma_f32_16x16x32_bf16(a0, b0, z[0][0], 0, 0, 0);
        z[0][1] = __builtin_amdgcn_mfma_f32_16x16x32_bf16(a0, b1, z[0][1], 0, 0, 0);
        z[1][0] = __builtin_amdgcn_mfma_f32_16x16x32_bf16(a1, b0, z[1][0], 0, 0, 0);
        z[1][1] = __builtin_amdgcn_mfma_f32_16x16x32_bf16(a1, b1, z[1][1], 0, 0, 0);
    }

    // + bias, accumulate |z|^2 per row (this wave's 32 cols)
    float bv0 = bias[nb + ln], bv1 = bias[nb + 16 + ln];
    float zv[2][2][4];
    float rp[2][4];
#pragma unroll
    for (int mi = 0; mi < 2; ++mi)
#pragma unroll
        for (int r = 0; r < 4; ++r) {
            float v0 = z[mi][0][r] + bv0;
            float v1 = z[mi][1][r] + bv1;
            zv[mi][0][r] = v0; zv[mi][1][r] = v1;
            rp[mi][r] = v0 * v0 + v1 * v1;
        }
#pragma unroll
    for (int mi = 0; mi < 2; ++mi)
#pragma unroll
        for (int r = 0; r < 4; ++r)
            for (int off = 1; off < 16; off <<= 1)
                rp[mi][r] += __shfl_xor(rp[mi][r], off, 64);   // reduce over 16 n-lanes
    if (ln == 0) {
#pragma unroll
        for (int mi = 0; mi < 2; ++mi)
#pragma unroll
            for (int r = 0; r < 4; ++r)
                s_part[(mi * 16 + q * 4 + r) * 4 + wave] = rp[mi][r];
    }
    __syncthreads();
    if (tid < 32) {
        float s = s_part[tid * 4] + s_part[tid * 4 + 1] + s_part[tid * 4 + 2] + s_part[tid * 4 + 3];
        float nrm = sqrtf(s);
        s_inv[tid] = 1.0f / fmaxf(nrm, 1e-12f);   // F.normalize eps
    }
    __syncthreads();

#pragma unroll
    for (int mi = 0; mi < 2; ++mi)
#pragma unroll
        for (int nj = 0; nj < 2; ++nj)
#pragma unroll
            for (int r = 0; r < 4; ++r) {
                int m = mi * 16 + q * 4 + r;
                int n = nb + nj * 16 + ln;
                out[(rowBase + m) * 128 + n] = zv[mi][nj][r] * s_inv[m];
            }
}

// ---------------------------------------------------------------- launch ----
extern "C" void kernel_launch(void* const* d_in, const int* in_sizes, int n_in,
                              void* d_out, int out_size, void* d_ws, size_t ws_size,
                              hipStream_t stream) {
    const float* x   = (const float*)d_in[0];   // [8192,128]
    const float* adj = (const float*)d_in[1];   // [8192,8192]
    const float* W   = (const float*)d_in[2];   // [128,128]
    const float* b   = (const float*)d_in[3];   // [128]
    float* out = (float*)d_out;

    unsigned short* yT  = (unsigned short*)d_ws;                         // 2 MB
    float*          dv  = (float*)((char*)d_ws + (2u << 20));            // 32 KB
    unsigned short* Wb  = (unsigned short*)((char*)d_ws + (2u << 20) + 32768);

    gcn_prep<<<8192 + 64, 256, 0, stream>>>(adj, x, W, yT, dv, Wb);
    gcn_main<<<256, 256, 0, stream>>>(adj, x, b, yT, dv, Wb, out);
}